// Round 5
// baseline (475.769 us; speedup 1.0000x reference)
//
#include <hip/hip_runtime.h>
#include <hip/hip_bf16.h>

typedef unsigned short u16;
typedef unsigned int   u32;

typedef __attribute__((ext_vector_type(8))) short bfrag;   // 8 bf16 (4 VGPRs)
typedef __attribute__((ext_vector_type(4))) float f32x4;   // MFMA acc

static __device__ __forceinline__ u16 f2bf(float f) {
    u32 u = __float_as_uint(f);
    return (u16)((u + 0x7fffu + ((u >> 16) & 1u)) >> 16);   // RNE
}
static __device__ __forceinline__ u32 pk2(float a, float b) {
    return (u32)f2bf(a) | ((u32)f2bf(b) << 16);
}
static __device__ __forceinline__ float bf2f(u16 h) {
    return __uint_as_float((u32)h << 16);
}

// ---------------- kernel 0: w_base [3,3,512,256] f32 -> wt [9][256co][512ci] bf16
__global__ __launch_bounds__(256) void prep_w_k(const float* __restrict__ wb,
                                                u16* __restrict__ wt)
{
    int i  = blockIdx.x * 256 + threadIdx.x;      // < 9*256*512
    int ci = i & 511;
    int co = (i >> 9) & 255;
    int pos = i >> 17;
    wt[i] = f2bf(wb[(size_t)((pos << 9) + ci) * 256 + co]);
}

// ---------------- fused conv(3x3,relu) + heads + sigmoid/mask/pack
// BM=128 pixels (2 image rows), BN=256 (all cout), 512 threads = 8 waves (2Mx4N).
// A: 4-row halo in LDS, staged once per 64-ch slice, reused for 9 positions.
// B: 32KB tile per (pos,cb), reg-staged double-buffer.
// Both LDS layouts granule(16B)-swizzled: g' = g ^ (axis & 7)  (m214 pattern).
union Smem {
    struct {
        u16 hal[4 * 66 * 64];   // 33792 B: [row 4][col 66][ch 64], swizzled
        u16 B[2][256 * 64];     // 65536 B: [co 256][ch 64], swizzled, dbuf
    } kl;                        // 99328 B
    u16   ft[256][128];          // 65536 B: feat^T bf16, rotated (head phase)
    float raw[128 * 45];         // 23040 B: head logits
};

template<int WMODE>   // 0: wt precomputed in ws; 1: convert w_base in-kernel
__global__ __launch_bounds__(512) void fused_k(
    const float* __restrict__ data,   // [8,64,64,512] f32
    const u16*   __restrict__ wt,     // [9][256][512] bf16 (WMODE 0)
    const float* __restrict__ wb,     // [3,3,512,256] f32 (WMODE 1)
    const float* __restrict__ bb,     // [256]
    const float* __restrict__ wc,     // [256,9]
    const float* __restrict__ bc,     // [9]
    const float* __restrict__ wr,     // [256,36]
    const float* __restrict__ br,     // [36]
    float*       __restrict__ out)    // [32768,45] f32
{
    __shared__ Smem sm;

    int bid = blockIdx.x;                         // 256 blocks
    int wg  = ((bid & 7) << 5) | (bid >> 3);      // XCD swizzle: 32-block chunk = 1 image per XCD
    int pm0 = wg << 7;                            // pixel base
    int img = wg >> 5;                            // image 0..7
    int y0  = (wg & 31) << 1;                     // image rows y0, y0+1

    int tid = threadIdx.x, lane = tid & 63, wid = tid >> 6;
    int wm = (wid >> 2) << 6, wn = (wid & 3) << 6;
    int fr = lane & 15, fg = lane >> 4;

    // ---- halo staging slot: thread -> (row 0..3, col 0..63, ch-half 0..1)
    int srow  = tid >> 7;
    int scol  = (tid >> 1) & 63;
    int shalf = tid & 1;
    int sy    = y0 + srow - 1;
    bool sok  = (sy >= 0) && (sy < 64);
    const float* hsrc = data + ((size_t)((img << 12) + (sy << 6) + scol) << 9)
                             + (shalf << 5);
    int  hcol = scol + 1;                          // LDS col (0 & 65 are zero borders)
    u16* hdst = &sm.kl.hal[(srow * 66 + hcol) << 6];

    // ---- B staging slot: thread -> (co 0..255, ch-half 0..1)
    int bco = tid >> 1, bhalf = tid & 1;

    f32x4  acc[4][4] = {};
    float4 hreg[8];
    uint4  breg[4];

    auto load_halo = [&](int cb) {
        #pragma unroll
        for (int j = 0; j < 8; ++j)
            hreg[j] = sok ? *(const float4*)(hsrc + (cb << 6) + (j << 2))
                          : make_float4(0.f, 0.f, 0.f, 0.f);
    };
    auto write_halo = [&]() {
        #pragma unroll
        for (int j = 0; j < 4; ++j) {
            int g = ((shalf << 2) | j) ^ (hcol & 7);
            *(uint4*)&hdst[g << 3] = make_uint4(
                pk2(hreg[2*j].x,   hreg[2*j].y),   pk2(hreg[2*j].z,   hreg[2*j].w),
                pk2(hreg[2*j+1].x, hreg[2*j+1].y), pk2(hreg[2*j+1].z, hreg[2*j+1].w));
        }
    };
    auto load_B = [&](int pos, int cb) {
        if (WMODE == 0) {
            const uint4* s = (const uint4*)(wt + ((size_t)pos << 17) +
                             ((size_t)bco << 9) + (cb << 6) + (bhalf << 5));
            #pragma unroll
            for (int j = 0; j < 4; ++j) breg[j] = s[j];
        } else {
            const float* s = wb + (size_t)((pos << 9) + (cb << 6) + (bhalf << 5)) * 256 + bco;
            #pragma unroll
            for (int j = 0; j < 4; ++j) {
                float f0 = s[(j*8+0) << 8], f1 = s[(j*8+1) << 8];
                float f2 = s[(j*8+2) << 8], f3 = s[(j*8+3) << 8];
                float f4 = s[(j*8+4) << 8], f5 = s[(j*8+5) << 8];
                float f6 = s[(j*8+6) << 8], f7 = s[(j*8+7) << 8];
                breg[j] = make_uint4(pk2(f0,f1), pk2(f2,f3), pk2(f4,f5), pk2(f6,f7));
            }
        }
    };
    auto write_B = [&](int buf) {
        u16* base = &sm.kl.B[buf][bco << 6];
        #pragma unroll
        for (int j = 0; j < 4; ++j) {
            int g = ((bhalf << 2) | j) ^ (bco & 7);
            *(uint4*)&base[g << 3] = breg[j];
        }
    };
    auto mfma_pos = [&](int dy, int dx, int buf) {
        int hr = (wm >> 6) + dy + 1;               // wave-uniform halo row
        #pragma unroll
        for (int kk = 0; kk < 2; ++kk) {
            bfrag av[4], bv[4];
            #pragma unroll
            for (int i = 0; i < 4; ++i) {
                int hc = (i << 4) + fr + dx + 1;                   // 0..65
                int ga = ((kk << 2) | fg) ^ (hc & 7);
                av[i] = *(const bfrag*)&sm.kl.hal[(((hr * 66 + hc) << 3) | ga) << 3];
                int co = wn + (i << 4) + fr;
                int gb = ((kk << 2) | fg) ^ (co & 7);
                bv[i] = *(const bfrag*)&sm.kl.B[buf][((co << 3) | gb) << 3];
            }
            #pragma unroll
            for (int mi = 0; mi < 4; ++mi)
                #pragma unroll
                for (int ni = 0; ni < 4; ++ni)
                    acc[mi][ni] = __builtin_amdgcn_mfma_f32_16x16x32_bf16(
                        av[mi], bv[ni], acc[mi][ni], 0, 0, 0);
        }
    };

    // ---- prologue: halo(cb0), zero borders, B(0,0), prefetch halo(cb1)
    load_halo(0);
    write_halo();
    if (tid < 64) {                                 // zero cols 0 and 65 (all 8 granules)
        int zr = tid >> 4, zc = ((tid >> 3) & 1) ? 65 : 0, zg = tid & 7;
        *(uint4*)&sm.kl.hal[(((zr * 66 + zc) << 3) | zg) << 3] = make_uint4(0,0,0,0);
    }
    load_B(0, 0);
    write_B(0);
    load_halo(1);                                   // flies during cb=0 pos loop
    int cur = 0;

    #pragma unroll 1
    for (int cb = 0; cb < 8; ++cb) {
        #pragma unroll
        for (int p = 0; p < 9; ++p) {
            __syncthreads();                        // publishes B[cur] & halo writes
            bool more = (p < 8) || (cb < 7);
            if (more) load_B(p < 8 ? p + 1 : 0, p < 8 ? cb : cb + 1);
            mfma_pos(p / 3 - 1, p % 3 - 1, cur);
            if (more) { write_B(cur ^ 1); cur ^= 1; }
        }
        if (cb < 7) {
            __syncthreads();                        // halo reads of this cb done
            write_halo();                           // hreg holds cb+1 slice
            if (cb < 6) load_halo(cb + 2);          // next prefetch
        }
    }
    __syncthreads();                                // conv LDS reads done (union reuse)

    // ---- epilogue: bias+relu -> ft[co][pix] bf16, rotation-swizzled ----
    #pragma unroll
    for (int ni = 0; ni < 4; ++ni) {
        int co = wn + (ni << 4) + fr;
        float bias = bb[co];
        int rot = (co & 31) << 2;
        #pragma unroll
        for (int mi = 0; mi < 4; ++mi) {
            int pb  = wm + (mi << 4) + (fg << 2);
            int col = (pb + rot) & 127;
            float r0 = fmaxf(acc[mi][ni][0] + bias, 0.f);
            float r1 = fmaxf(acc[mi][ni][1] + bias, 0.f);
            float r2 = fmaxf(acc[mi][ni][2] + bias, 0.f);
            float r3 = fmaxf(acc[mi][ni][3] + bias, 0.f);
            *(uint2*)&sm.ft[co][col] = make_uint2(pk2(r0, r1), pk2(r2, r3));
        }
    }
    __syncthreads();

    // ---- head dot: wave w owns channels [6w, 6w+6); lanes = pixels (2 passes) ----
    int wchx = __builtin_amdgcn_readfirstlane(wid) * 6;
    float sv[2][6];
    #pragma unroll
    for (int pass = 0; pass < 2; ++pass) {
        int pix = lane + (pass << 6);
        float a6[6];
        #pragma unroll
        for (int j = 0; j < 6; ++j) {
            int ch = wchx + j;
            a6[j] = (ch < 36) ? br[ch] : ((ch < 45) ? bc[ch - 36] : 0.f);
        }
        #pragma unroll 4
        for (int c = 0; c < 256; ++c) {
            int col = (pix + ((c & 31) << 2)) & 127;
            float f = bf2f(sm.ft[c][col]);
            #pragma unroll
            for (int j = 0; j < 6; ++j) {
                int ch = wchx + j;
                if (ch < 36)      a6[j] = fmaf(f, wr[c * 36 + ch], a6[j]);
                else if (ch < 45) a6[j] = fmaf(f, wc[c * 9 + ch - 36], a6[j]);
            }
        }
        #pragma unroll
        for (int j = 0; j < 6; ++j) sv[pass][j] = a6[j];
    }
    __syncthreads();
    #pragma unroll
    for (int pass = 0; pass < 2; ++pass) {
        int pix = lane + (pass << 6);
        #pragma unroll
        for (int j = 0; j < 6; ++j) {
            int ch = wchx + j;
            if (ch < 45) sm.raw[pix * 45 + ch] = sv[pass][j];
        }
    }
    __syncthreads();

    // ---- final: sigmoid + mask + pack -> f32 out ----
    {
        int pix = tid >> 2, q = tid & 3;
        const float* rp = &sm.raw[pix * 45];
        float* op = out + (size_t)(pm0 + pix) * 45;
        int na = (q == 3) ? 3 : 2;
        int a0 = (q == 3) ? 6 : (q << 1);
        for (int t = 0; t < na; ++t) {
            int a = a0 + t;
            float lg  = rp[36 + a];
            float obj = 1.f / (1.f + __expf(-lg));
            float b0 = rp[4*a], b1 = rp[4*a+1], b2 = rp[4*a+2], b3 = rp[4*a+3];
            bool m = (obj > 0.7f) && (b2 > 10.f) && (b3 > 10.f);
            op[4*a    ] = m ? b0 : 0.f;
            op[4*a + 1] = m ? b1 : 0.f;
            op[4*a + 2] = m ? b2 : 0.f;
            op[4*a + 3] = m ? b3 : 0.f;
            op[36 + a ] = obj;
        }
    }
}

extern "C" void kernel_launch(void* const* d_in, const int* in_sizes, int n_in,
                              void* d_out, int out_size, void* d_ws, size_t ws_size,
                              hipStream_t stream)
{
    const float* data = (const float*)d_in[0];
    const float* wb   = (const float*)d_in[1];
    const float* bb   = (const float*)d_in[2];
    const float* wc   = (const float*)d_in[3];
    const float* bcl  = (const float*)d_in[4];
    const float* wr   = (const float*)d_in[5];
    const float* brg  = (const float*)d_in[6];
    float* out = (float*)d_out;

    const size_t WT_BYTES = (size_t)9 * 256 * 512 * 2;   // 2,359,296

    if (ws_size >= WT_BYTES) {
        u16* wt = (u16*)d_ws;
        prep_w_k<<<4608, 256, 0, stream>>>(wb, wt);
        fused_k<0><<<256, 512, 0, stream>>>(data, wt, wb, bb, wc, bcl, wr, brg, out);
    } else {
        fused_k<1><<<256, 512, 0, stream>>>(data, (const u16*)nullptr, wb,
                                            bb, wc, bcl, wr, brg, out);
    }
}

// Round 6
// 360.898 us; speedup vs baseline: 1.3183x; 1.3183x over previous
//
#include <hip/hip_runtime.h>
#include <hip/hip_bf16.h>

typedef unsigned short u16;
typedef unsigned int   u32;

typedef __attribute__((ext_vector_type(8))) short bfrag;   // 8 bf16 (4 VGPRs)
typedef __attribute__((ext_vector_type(4))) float f32x4;   // MFMA acc

static __device__ __forceinline__ u16 f2bf(float f) {
    u32 u = __float_as_uint(f);
    return (u16)((u + 0x7fffu + ((u >> 16) & 1u)) >> 16);   // RNE
}
static __device__ __forceinline__ u32 pk2(float a, float b) {
    return (u32)f2bf(a) | ((u32)f2bf(b) << 16);
}
static __device__ __forceinline__ float bf2f(u16 h) {
    return __uint_as_float((u32)h << 16);
}

// ---------------- kernel 0: w_base [3,3,512,256] f32 -> wt [9][256co][512ci] bf16
__global__ __launch_bounds__(256) void prep_w_k(const float* __restrict__ wb,
                                                u16* __restrict__ wt)
{
    int i  = blockIdx.x * 256 + threadIdx.x;      // < 9*256*512
    int ci = i & 511;
    int co = (i >> 9) & 255;
    int pos = i >> 17;
    wt[i] = f2bf(wb[(size_t)((pos << 9) + ci) * 256 + co]);
}

// ---------------- fused conv(3x3,relu) + heads + sigmoid/mask/pack
// BM=64 pixels (1 image row), BN=256 (all cout), 256 threads = 4 waves (1M x 4N).
// A: 3-row halo in LDS (16B-granule XOR swizzle), staged once per 64-ch slice,
//    reused for 9 positions with NO barriers inside the position loop.
// B: global -> registers per (pos, kk) fragment; no LDS for B at all.
// 512 blocks -> 2 independent blocks per CU (two barrier domains).
union Smem {
    u16   hal[3 * 66 * 64];    // 25344 B: [row 3][col 66][ch 64], swizzled
    u16   ft[256][64];         // 32768 B: feat^T bf16, rotated (head phase)
    float raw[64 * 45];        // 11520 B: head logits
};

template<int WMODE>   // 0: wt precomputed in ws; 1: gather-convert w_base in-kernel
__global__ __launch_bounds__(256, 2) void fused_k(
    const float* __restrict__ data,   // [8,64,64,512] f32
    const u16*   __restrict__ wt,     // [9][256][512] bf16 (WMODE 0)
    const float* __restrict__ wb,     // [3,3,512,256] f32 (WMODE 1)
    const float* __restrict__ bb,     // [256]
    const float* __restrict__ wc,     // [256,9]
    const float* __restrict__ bc,     // [9]
    const float* __restrict__ wr,     // [256,36]
    const float* __restrict__ br,     // [36]
    float*       __restrict__ out)    // [32768,45] f32
{
    __shared__ Smem sm;

    int bid = blockIdx.x;                         // 512 blocks
    int wg  = ((bid & 7) << 6) | (bid >> 3);      // XCD swizzle: 64-chunk = 1 image/XCD
    int pm0 = wg << 6;                            // pixel base (64 pixels/block)
    int img = wg >> 6;                            // image 0..7
    int y0  = wg & 63;                            // image row

    int tid = threadIdx.x, lane = tid & 63, wid = tid >> 6;
    int wn = wid << 6;                            // wave's 64-co slice
    int fr = lane & 15, fg = lane >> 4;

    f32x4 acc[4][4] = {};

    #pragma unroll 1
    for (int cb = 0; cb < 8; ++cb) {
        __syncthreads();                          // prior cb's halo reads done
        // ---- stage 3-row halo for ch slice cb: 3 passes of 256 threads ----
        #pragma unroll
        for (int t = 0; t < 3; ++t) {
            int lin = t * 256 + tid;              // 0..767
            int row = lin >> 8;                   // 0..2
            int col = (lin >> 2) & 63;            // 0..63
            int cq  = lin & 3;                    // 16-ch quarter
            int sy  = y0 + row - 1;
            bool ok = (sy >= 0) && (sy < 64);
            float4 v0, v1, v2, v3;
            if (ok) {
                const float4* s = (const float4*)(data +
                    ((size_t)((img << 12) + (sy << 6) + col) << 9) + (cb << 6) + (cq << 4));
                v0 = s[0]; v1 = s[1]; v2 = s[2]; v3 = s[3];
            } else {
                v0 = v1 = v2 = v3 = make_float4(0.f, 0.f, 0.f, 0.f);
            }
            int hc = col + 1;                     // LDS col (0 & 65 are zero borders)
            u16* base = &sm.hal[(row * 66 + hc) << 6];
            int g0 = ((cq << 1) | 0) ^ (hc & 7);
            int g1 = ((cq << 1) | 1) ^ (hc & 7);
            *(uint4*)&base[g0 << 3] = make_uint4(pk2(v0.x,v0.y), pk2(v0.z,v0.w),
                                                 pk2(v1.x,v1.y), pk2(v1.z,v1.w));
            *(uint4*)&base[g1 << 3] = make_uint4(pk2(v2.x,v2.y), pk2(v2.z,v2.w),
                                                 pk2(v3.x,v3.y), pk2(v3.z,v3.w));
        }
        if (tid < 48) {                           // zero cols 0,65 (3 rows x 8 granules)
            int zr = tid >> 4, zrem = tid & 15;
            int zc = (zrem >> 3) ? 65 : 0, zg = zrem & 7;
            *(uint4*)&sm.hal[(((zr * 66 + zc) << 3) | zg) << 3] = make_uint4(0,0,0,0);
        }
        __syncthreads();

        // ---- 9 positions, barrier-free: B global->reg, A from halo LDS ----
        #pragma unroll
        for (int pos = 0; pos < 9; ++pos) {
            int dy = pos / 3 - 1, dx = pos % 3 - 1;
            bfrag bv[2][4];
            if (WMODE == 0) {
                #pragma unroll
                for (int kk = 0; kk < 2; ++kk)
                    #pragma unroll
                    for (int i = 0; i < 4; ++i)
                        bv[kk][i] = *(const bfrag*)(wt + ((size_t)pos << 17) +
                            ((size_t)(wn + (i << 4) + fr) << 9) + (cb << 6) +
                            (kk << 5) + (fg << 3));
            } else {
                #pragma unroll
                for (int kk = 0; kk < 2; ++kk)
                    #pragma unroll
                    for (int i = 0; i < 4; ++i) {
                        int co = wn + (i << 4) + fr;
                        const float* s = wb +
                            (size_t)((pos << 9) + (cb << 6) + (kk << 5) + (fg << 3)) * 256 + co;
                        union { short sh[8]; bfrag v; } tb;
                        #pragma unroll
                        for (int j = 0; j < 8; ++j) tb.sh[j] = (short)f2bf(s[(size_t)j << 8]);
                        bv[kk][i] = tb.v;
                    }
            }
            int hr = dy + 1;
            bfrag av[2][4];
            #pragma unroll
            for (int kk = 0; kk < 2; ++kk)
                #pragma unroll
                for (int i = 0; i < 4; ++i) {
                    int hc = (i << 4) + fr + dx + 1;              // 0..65
                    int g  = ((kk << 2) | fg) ^ (hc & 7);
                    av[kk][i] = *(const bfrag*)&sm.hal[(((hr * 66 + hc) << 3) | g) << 3];
                }
            #pragma unroll
            for (int kk = 0; kk < 2; ++kk)
                #pragma unroll
                for (int mi = 0; mi < 4; ++mi)
                    #pragma unroll
                    for (int ni = 0; ni < 4; ++ni)
                        acc[mi][ni] = __builtin_amdgcn_mfma_f32_16x16x32_bf16(
                            av[kk][mi], bv[kk][ni], acc[mi][ni], 0, 0, 0);
        }
    }
    __syncthreads();                              // halo reads done (union reuse)

    // ---- epilogue: bias+relu -> ft[co][pix] bf16, rotation-swizzled ----
    #pragma unroll
    for (int ni = 0; ni < 4; ++ni) {
        int co = wn + (ni << 4) + fr;
        float bias = bb[co];
        int rot = (co & 15) << 2;
        #pragma unroll
        for (int mi = 0; mi < 4; ++mi) {
            int pb  = (mi << 4) + (fg << 2);
            int col = (pb + rot) & 63;
            float r0 = fmaxf(acc[mi][ni][0] + bias, 0.f);
            float r1 = fmaxf(acc[mi][ni][1] + bias, 0.f);
            float r2 = fmaxf(acc[mi][ni][2] + bias, 0.f);
            float r3 = fmaxf(acc[mi][ni][3] + bias, 0.f);
            *(uint2*)&sm.ft[co][col] = make_uint2(pk2(r0, r1), pk2(r2, r3));
        }
    }
    __syncthreads();

    // ---- head dot: wave w owns channels [12w, 12w+12); lane = pixel ----
    int wchx = __builtin_amdgcn_readfirstlane(wid) * 12;
    float a12[12];
    #pragma unroll
    for (int j = 0; j < 12; ++j) {
        int ch = wchx + j;
        a12[j] = (ch < 36) ? br[ch] : ((ch < 45) ? bc[ch - 36] : 0.f);
    }
    #pragma unroll 4
    for (int c = 0; c < 256; ++c) {
        int col = (lane + ((c & 15) << 2)) & 63;  // undo rotation
        float f = bf2f(sm.ft[c][col]);
        #pragma unroll
        for (int j = 0; j < 12; ++j) {
            int ch = wchx + j;                    // wave-uniform
            if (ch < 36)      a12[j] = fmaf(f, wr[c * 36 + ch], a12[j]);
            else if (ch < 45) a12[j] = fmaf(f, wc[c * 9 + ch - 36], a12[j]);
        }
    }
    __syncthreads();                              // ft reads done (union reuse)
    #pragma unroll
    for (int j = 0; j < 12; ++j) {
        int ch = wchx + j;
        if (ch < 45) sm.raw[lane * 45 + ch] = a12[j];
    }
    __syncthreads();

    // ---- final: sigmoid + mask + pack -> f32 out ----
    {
        int pix = tid >> 2, q = tid & 3;
        const float* rp = &sm.raw[pix * 45];
        float* op = out + (size_t)(pm0 + pix) * 45;
        int na = (q == 3) ? 3 : 2;
        int a0 = (q == 3) ? 6 : (q << 1);
        for (int t = 0; t < na; ++t) {
            int a = a0 + t;
            float lg  = rp[36 + a];
            float obj = 1.f / (1.f + __expf(-lg));
            float b0 = rp[4*a], b1 = rp[4*a+1], b2 = rp[4*a+2], b3 = rp[4*a+3];
            bool m = (obj > 0.7f) && (b2 > 10.f) && (b3 > 10.f);
            op[4*a    ] = m ? b0 : 0.f;
            op[4*a + 1] = m ? b1 : 0.f;
            op[4*a + 2] = m ? b2 : 0.f;
            op[4*a + 3] = m ? b3 : 0.f;
            op[36 + a ] = obj;
        }
    }
}

extern "C" void kernel_launch(void* const* d_in, const int* in_sizes, int n_in,
                              void* d_out, int out_size, void* d_ws, size_t ws_size,
                              hipStream_t stream)
{
    const float* data = (const float*)d_in[0];
    const float* wb   = (const float*)d_in[1];
    const float* bb   = (const float*)d_in[2];
    const float* wc   = (const float*)d_in[3];
    const float* bcl  = (const float*)d_in[4];
    const float* wr   = (const float*)d_in[5];
    const float* brg  = (const float*)d_in[6];
    float* out = (float*)d_out;

    const size_t WT_BYTES = (size_t)9 * 256 * 512 * 2;   // 2,359,296

    if (ws_size >= WT_BYTES) {
        u16* wt = (u16*)d_ws;
        prep_w_k<<<4608, 256, 0, stream>>>(wb, wt);
        fused_k<0><<<512, 256, 0, stream>>>(data, wt, wb, bb, wc, bcl, wr, brg, out);
    } else {
        fused_k<1><<<512, 256, 0, stream>>>(data, (const u16*)nullptr, wb,
                                            bb, wc, bcl, wr, brg, out);
    }
}